// Round 1
// baseline (2491.249 us; speedup 1.0000x reference)
//
#include <hip/hip_runtime.h>
#include <hip/hip_bf16.h>

// ---------------------------------------------------------------------------
// C[M,N] = A[M,K] @ W[N,K]^T + bias[N]   (f32, 64x64 tile, 4x4 microtile)
// N must be a multiple of 64, K a multiple of 16. M is bounds-checked.
// ---------------------------------------------------------------------------
__global__ __launch_bounds__(256, 2)
void gemm_bt(const float* __restrict__ A, const float* __restrict__ W,
             const float* __restrict__ bias, float* __restrict__ C,
             int M, int N, int K) {
  __shared__ float As[16][68];   // [k][m], pad to 68 to break conflicts
  __shared__ float Ws[16][68];   // [k][n]
  const int t  = threadIdx.x;
  const int tx = t & 15, ty = t >> 4;
  const int m0 = blockIdx.y * 64, n0 = blockIdx.x * 64;
  const int lr = t >> 2;          // 0..63: row within tile
  const int lk = (t & 3) * 4;     // 0,4,8,12: k offset

  float acc[4][4];
  #pragma unroll
  for (int i = 0; i < 4; ++i)
    #pragma unroll
    for (int j = 0; j < 4; ++j) acc[i][j] = 0.f;

  for (int k0 = 0; k0 < K; k0 += 16) {
    int am = m0 + lr; if (am > M - 1) am = M - 1;
    const float4 a4 = *(const float4*)&A[(size_t)am * K + k0 + lk];
    const float4 w4 = *(const float4*)&W[(size_t)(n0 + lr) * K + k0 + lk];
    __syncthreads();                       // previous iter's reads done
    As[lk + 0][lr] = a4.x; As[lk + 1][lr] = a4.y;
    As[lk + 2][lr] = a4.z; As[lk + 3][lr] = a4.w;
    Ws[lk + 0][lr] = w4.x; Ws[lk + 1][lr] = w4.y;
    Ws[lk + 2][lr] = w4.z; Ws[lk + 3][lr] = w4.w;
    __syncthreads();
    #pragma unroll
    for (int kk = 0; kk < 16; ++kk) {
      const float4 av = *(const float4*)&As[kk][ty * 4];
      const float4 wv = *(const float4*)&Ws[kk][tx * 4];
      const float ar[4] = {av.x, av.y, av.z, av.w};
      const float wr[4] = {wv.x, wv.y, wv.z, wv.w};
      #pragma unroll
      for (int i = 0; i < 4; ++i)
        #pragma unroll
        for (int j = 0; j < 4; ++j) acc[i][j] = fmaf(ar[i], wr[j], acc[i][j]);
    }
  }
  #pragma unroll
  for (int i = 0; i < 4; ++i) {
    const int m = m0 + ty * 4 + i;
    if (m < M) {
      #pragma unroll
      for (int j = 0; j < 4; ++j) {
        const int n = n0 + tx * 4 + j;
        C[(size_t)m * N + n] = acc[i][j] + bias[n];
      }
    }
  }
}

// ---------------------------------------------------------------------------
// Fused continuous-position-bias MLP + flash attention.
// Block = (b, 8 q-rows). 256 threads. Chunks of 32 keys.
//   QK role:  thread = (qi = t>>5, kk = t&31), pair index == t
//   MLP role: j-split: 8 lanes (jg = t&7) each own 8 hidden units, weights in
//             registers; shuffle-reduce; thread t keeps cpb of pair t.
//   PV role:  thread = output dim e = t (h = e>>5).
// ---------------------------------------------------------------------------
#define QT 8
#define KC 32

__global__ __launch_bounds__(256, 2)
void attn_cpb(const float* __restrict__ qbuf,   // [B,900,256]
              const float* __restrict__ kvbuf,  // [B,1024,512] (k | v)
              const float* __restrict__ dist,   // [B,900,1024,2]
              const unsigned char* __restrict__ mask, // [B,1024]
              const float* __restrict__ Wc1, const float* __restrict__ bc1,
              const float* __restrict__ Wc2, const float* __restrict__ bc2,
              float* __restrict__ obuf) {       // [B,900,256]
  __shared__ float qs[QT][256];        // 8 KB
  __shared__ float ks[KC][256];        // 32 KB, xor-swizzled columns
  __shared__ float ps[8][KC][12];      // p[h][kk][qi], pad 12 -> 12 KB
  __shared__ float mstate[QT][8], lstate[QT][8], astate[QT][8];

  const int t  = threadIdx.x;
  const int b  = blockIdx.x / 113;
  const int q0 = (blockIdx.x % 113) * QT;

  // --- register-resident MLP weights (j-split: 8 hidden units per lane) ---
  const int jg = t & 7;
  const int js = jg * 8;
  float w1x[8], w1y[8], b1r[8], w2r[8][8], b2r[8];
  #pragma unroll
  for (int jl = 0; jl < 8; ++jl) {
    const float2 w = *(const float2*)&Wc1[(js + jl) * 2];
    w1x[jl] = w.x; w1y[jl] = w.y;
    b1r[jl] = bc1[js + jl];
  }
  #pragma unroll
  for (int h = 0; h < 8; ++h) {
    b2r[h] = bc2[h];
    #pragma unroll
    for (int jl = 0; jl < 8; ++jl) w2r[h][jl] = Wc2[h * 64 + js + jl];
  }

  // --- stage q rows (clamped; tail rows duplicated, stores guarded) ---
  #pragma unroll
  for (int j = 0; j < 2; ++j) {
    const int f = t + 256 * j;          // 0..511
    const int row = f >> 6, c = (f & 63) * 4;
    int q = q0 + row; if (q > 899) q = 899;
    *(float4*)&qs[row][c] =
        *(const float4*)&qbuf[((size_t)(b * 900 + q)) * 256 + c];
  }
  if (t < 64) {
    mstate[t >> 3][t & 7] = -1e30f;
    lstate[t >> 3][t & 7] = 0.f;
  }
  float O[QT];
  #pragma unroll
  for (int i = 0; i < QT; ++i) O[i] = 0.f;

  const int qi  = t >> 5, kk = t & 31;
  const int swz = (kk & 7) << 2;
  __syncthreads();

  for (int c = 0; c < 1024 / KC; ++c) {
    const int k0 = c * KC;
    // ---- stage K chunk into LDS (xor-swizzle columns by row) ----
    #pragma unroll
    for (int j = 0; j < 8; ++j) {
      const int f = t + 256 * j;        // 0..2047
      const int row = f >> 6, col = (f & 63) * 4;
      const int sc = col ^ ((row & 7) << 2);
      *(float4*)&ks[row][sc] =
          *(const float4*)&kvbuf[((size_t)(b * 1024 + k0 + row)) * 512 + col];
    }
    __syncthreads();

    // ---- cpb MLP, j-split + shuffle reduce ----
    float cpk[8];
    #pragma unroll
    for (int h = 0; h < 8; ++h) cpk[h] = 0.f;
    #pragma unroll
    for (int pp = 0; pp < 8; ++pp) {
      const int pair = (t >> 3) * 8 + pp;        // all 8 lanes of group: same pair
      const int pqi = pair >> 5, pkk = pair & 31;
      int q = q0 + pqi; if (q > 899) q = 899;
      const float2 d2 = *(const float2*)
          &dist[(((size_t)(b * 900 + q)) * 1024 + (size_t)(k0 + pkk)) * 2];
      float cp[8];
      #pragma unroll
      for (int h = 0; h < 8; ++h) cp[h] = 0.f;
      #pragma unroll
      for (int jl = 0; jl < 8; ++jl) {
        const float hv =
            fmaxf(fmaf(w1x[jl], d2.x, fmaf(w1y[jl], d2.y, b1r[jl])), 0.f);
        #pragma unroll
        for (int h = 0; h < 8; ++h) cp[h] = fmaf(w2r[h][jl], hv, cp[h]);
      }
      #pragma unroll
      for (int h = 0; h < 8; ++h) {
        cp[h] += __shfl_xor(cp[h], 1);
        cp[h] += __shfl_xor(cp[h], 2);
        cp[h] += __shfl_xor(cp[h], 4);
      }
      if (pp == jg) {                    // pair == t: keep own pair's cpb
        #pragma unroll
        for (int h = 0; h < 8; ++h) cpk[h] = cp[h] + b2r[h];
      }
    }

    // ---- QK dot products ----
    float acc[8];
    #pragma unroll
    for (int h = 0; h < 8; ++h) acc[h] = 0.f;
    #pragma unroll
    for (int d4 = 0; d4 < 8; ++d4) {
      #pragma unroll
      for (int h = 0; h < 8; ++h) {
        const int d = h * 32 + d4 * 4;
        const float4 q4 = *(const float4*)&qs[qi][d];
        const float4 k4 = *(const float4*)&ks[kk][d ^ swz];
        acc[h] = fmaf(q4.x, k4.x, acc[h]);
        acc[h] = fmaf(q4.y, k4.y, acc[h]);
        acc[h] = fmaf(q4.z, k4.z, acc[h]);
        acc[h] = fmaf(q4.w, k4.w, acc[h]);
      }
    }

    // ---- scores + online softmax (32-lane group per (qi,h)) ----
    const bool msk = mask[b * 1024 + k0 + kk] != 0;
    #pragma unroll
    for (int h = 0; h < 8; ++h) {
      const float sh =
          msk ? -1e30f : fmaf(acc[h], 0.17677669529663687f, cpk[h]);
      float cmax = sh;
      cmax = fmaxf(cmax, __shfl_xor(cmax, 1));
      cmax = fmaxf(cmax, __shfl_xor(cmax, 2));
      cmax = fmaxf(cmax, __shfl_xor(cmax, 4));
      cmax = fmaxf(cmax, __shfl_xor(cmax, 8));
      cmax = fmaxf(cmax, __shfl_xor(cmax, 16));
      const float mold = mstate[qi][h];
      const float mnew = fmaxf(mold, cmax);
      const float al   = __expf(mold - mnew);
      const float p    = __expf(sh - mnew);
      ps[h][kk][qi] = p;
      float psum = p;
      psum += __shfl_xor(psum, 1);
      psum += __shfl_xor(psum, 2);
      psum += __shfl_xor(psum, 4);
      psum += __shfl_xor(psum, 8);
      psum += __shfl_xor(psum, 16);
      if (kk == 0) {
        mstate[qi][h] = mnew;
        lstate[qi][h] = lstate[qi][h] * al + psum;
        astate[qi][h] = al;
      }
    }
    __syncthreads();

    // ---- PV: thread owns output dim e = t ----
    const int he = t >> 5;
    #pragma unroll
    for (int i = 0; i < QT; ++i) O[i] *= astate[i][he];
    const float* vp = kvbuf + ((size_t)(b * 1024 + k0)) * 512 + 256 + t;
    #pragma unroll 8
    for (int k2 = 0; k2 < KC; ++k2) {
      const float v   = vp[(size_t)k2 * 512];
      const float4 pa = *(const float4*)&ps[he][k2][0];
      const float4 pb = *(const float4*)&ps[he][k2][4];
      O[0] = fmaf(pa.x, v, O[0]); O[1] = fmaf(pa.y, v, O[1]);
      O[2] = fmaf(pa.z, v, O[2]); O[3] = fmaf(pa.w, v, O[3]);
      O[4] = fmaf(pb.x, v, O[4]); O[5] = fmaf(pb.y, v, O[5]);
      O[6] = fmaf(pb.z, v, O[6]); O[7] = fmaf(pb.w, v, O[7]);
    }
    __syncthreads();
  }

  const int he = t >> 5;
  #pragma unroll
  for (int i = 0; i < QT; ++i) {
    const int q = q0 + i;
    if (q < 900)
      obuf[((size_t)(b * 900 + q)) * 256 + t] = O[i] / lstate[i][he];
  }
}

// ---------------------------------------------------------------------------
extern "C" void kernel_launch(void* const* d_in, const int* in_sizes, int n_in,
                              void* d_out, int out_size, void* d_ws, size_t ws_size,
                              hipStream_t stream) {
  const float* nodes  = (const float*)d_in[0];
  const float* images = (const float*)d_in[1];
  const unsigned char* mask = (const unsigned char*)d_in[2];
  const float* dist   = (const float*)d_in[3];
  const float* Wq     = (const float*)d_in[4];
  const float* bq     = (const float*)d_in[5];
  const float* Wkv    = (const float*)d_in[6];
  const float* bkv    = (const float*)d_in[7];
  const float* Wc1    = (const float*)d_in[8];
  const float* bc1    = (const float*)d_in[9];
  const float* Wc2    = (const float*)d_in[10];
  const float* bc2    = (const float*)d_in[11];
  const float* Wo     = (const float*)d_in[12];
  const float* bo     = (const float*)d_in[13];
  float* out = (float*)d_out;

  float* qbuf  = (float*)d_ws;                 // 3600*256
  float* kvbuf = qbuf + 3600 * 256;            // 4096*512
  float* obuf  = kvbuf + 4096 * 512;           // 3600*256

  gemm_bt<<<dim3(4, 57), 256, 0, stream>>>(nodes,  Wq,  bq,  qbuf,  3600, 256, 256);
  gemm_bt<<<dim3(8, 64), 256, 0, stream>>>(images, Wkv, bkv, kvbuf, 4096, 512, 256);
  attn_cpb<<<dim3(452), 256, 0, stream>>>(qbuf, kvbuf, dist, mask,
                                          Wc1, bc1, Wc2, bc2, obuf);
  gemm_bt<<<dim3(4, 57), 256, 0, stream>>>(obuf, Wo, bo, out, 3600, 256, 256);
}